// Round 8
// baseline (173.902 us; speedup 1.0000x reference)
//
#include <hip/hip_runtime.h>
#include <hip/hip_bf16.h>

#define NQH 64
#define NKVH 8
#define DH 64
#define SEQ 1024
#define HID 2880
#define QKV_N 5120   // (NQ+2*NKV)*DH
#define ATTN_N 4096  // NQ*DH
#define WIN 128
#define WO_NPAD 2944 // 23*128
#define SCALE_F 0.125f

typedef __attribute__((ext_vector_type(8))) __bf16 bf16x8;
typedef __attribute__((ext_vector_type(4))) float f32x4;

#define GLOAD_LDS16(g, l) \
    __builtin_amdgcn_global_load_lds((const __attribute__((address_space(1))) void*)(g), \
                                     (__attribute__((address_space(3))) void*)(l), 16, 0, 0)

__device__ __forceinline__ ushort f2bf(float x) {
    union { float f; unsigned int u; } c; c.f = x;
    unsigned int u = c.u;
    unsigned int r = (u + 0x7FFFu + ((u >> 16) & 1u)) >> 16;
    return (ushort)r;
}

// ---------------------------------------------------------------- convert (plain)
__global__ __launch_bounds__(256) void convert_f32_bf16(
    const float* __restrict__ in, ushort* __restrict__ out, int n4)
{
    int idx = blockIdx.x * blockDim.x + threadIdx.x;
    int stride = gridDim.x * blockDim.x;
    for (int i = idx; i < n4; i += stride) {
        float4 v = reinterpret_cast<const float4*>(in)[i];
        ushort4 o;
        o.x = f2bf(v.x); o.y = f2bf(v.y); o.z = f2bf(v.z); o.w = f2bf(v.w);
        reinterpret_cast<ushort4*>(out)[i] = o;
    }
}

// ---------------------------------------------------------------- reduce: o = a + b (f32x4)
__global__ __launch_bounds__(256) void reduce_add(
    const float4* __restrict__ a, const float4* __restrict__ b,
    float4* __restrict__ o, int n4)
{
    int idx = blockIdx.x * blockDim.x + threadIdx.x;
    int stride = gridDim.x * blockDim.x;
    for (int i = idx; i < n4; i += stride) {
        float4 x = a[i], y = b[i];
        float4 r;
        r.x = x.x + y.x; r.y = x.y + y.y; r.z = x.z + y.z; r.w = x.w + y.w;
        o[i] = r;
    }
}

// ---------------------------------------------------------------- transpose+convert
// in: [K][N] f32  ->  out: [Npad][K] bf16 (rows >= N zero-filled). K,Npad multiples of 64.
__global__ __launch_bounds__(256) void transpose_convert(
    const float* __restrict__ in, ushort* __restrict__ out, int K, int N)
{
    __shared__ ushort tile[64][80];   // row stride 160B (16B-aligned for uint4)
    const int bk = blockIdx.x * 64;   // k tile origin
    const int bn = blockIdx.y * 64;   // n tile origin
    const int tid = threadIdx.x;
    const bool inb = bn < N;          // whole tile valid or whole tile pad (N % 64 == 0)

#pragma unroll
    for (int it = 0; it < 4; ++it) {
        int r = it * 16 + (tid >> 4);         // k offset 0..63
        int c4 = (tid & 15) * 4;              // n offset
        float4 v = make_float4(0.f, 0.f, 0.f, 0.f);
        if (inb) v = *(const float4*)&in[(size_t)(bk + r) * N + bn + c4];
        tile[c4 + 0][r] = f2bf(v.x);
        tile[c4 + 1][r] = f2bf(v.y);
        tile[c4 + 2][r] = f2bf(v.z);
        tile[c4 + 3][r] = f2bf(v.w);
    }
    __syncthreads();
#pragma unroll
    for (int it = 0; it < 2; ++it) {
        int nr = it * 32 + (tid >> 3);        // n offset 0..63
        int c8 = (tid & 7) * 8;               // k offset
        uint4 v = *(const uint4*)&tile[nr][c8];
        *(uint4*)&out[(size_t)(bn + nr) * K + bk + c8] = v;
    }
}

// ---------------------------------------------------------------- GEMM 64x128, BK=32, split-K x2
// A: [M][Kld] bf16, BT: [Npad][Kld] bf16. Partial C (f32) for K-half kz = blockIdx.z:
//   C[kz*cstride + row*ldC + col] = sum_{k in half} A.B  (+ bias if kz==0) (+rope if ROPE)
// RoPE is LINEAR, so applying it per-half and summing in reduce_add is exact.
// 256 threads = 4 waves, wave tile 32x64 (2x4 frags), 8 MFMA/step. LDS 24KB -> 6 blocks/CU.
// LDS row = 32 el = 64B; chunk swizzle: slot = chunk ^ ((row>>1)&3) -> balanced banks.
template<bool ROPE>
__global__ __launch_bounds__(256) void gemm_sk(
    const ushort* __restrict__ A, const ushort* __restrict__ BT,
    const float* __restrict__ bias, float* __restrict__ C,
    int Khalf, int Kld, int ldC, int Nreal, size_t cstride,
    const float* __restrict__ cosp, const float* __restrict__ sinp)
{
    __shared__ ushort Al[2 * 2048];   // 2 x 4 KB (64x32)
    __shared__ ushort Bl[2 * 4096];   // 2 x 8 KB (128x32)
    const int t = threadIdx.x;
    const int lane = t & 63;
    const int w = t >> 6;
    const int wr = w >> 1, wc = w & 1;
    const int g4 = lane >> 4;
    const int r15 = lane & 15;
    const int kz = blockIdx.z;

    // bijective XCD swizzle per z-slice (gx*gy % 8 == 0)
    const int flat = blockIdx.x + gridDim.x * blockIdx.y;
    const int per = (gridDim.x * gridDim.y) >> 3;
    const int virt = (flat & 7) * per + (flat >> 3);
    const int m0 = (virt & 15) * 64;
    const int n0 = (virt >> 4) * 128;

    // ---- staging (inverse-swizzled global source, linear LDS dest)
    // A: 64 rows x 4 chunks = 256 units (1/thread). B: 128 rows x 4 = 512 (2/thread).
    const ushort *aS, *bS0, *bS1;
    int aO, bO0, bO1;
    {
        int rowA = t >> 2;
        int chA = (t & 3) ^ ((rowA >> 1) & 3);
        aS = A + (size_t)(m0 + rowA) * Kld + kz * Khalf + chA * 8;
        aO = t * 8;
        int lin0 = t, lin1 = 256 + t;
        int rowB0 = lin0 >> 2, rowB1 = lin1 >> 2;
        int chB0 = (lin0 & 3) ^ ((rowB0 >> 1) & 3);
        int chB1 = (lin1 & 3) ^ ((rowB1 >> 1) & 3);
        bS0 = BT + (size_t)(n0 + rowB0) * Kld + kz * Khalf + chB0 * 8;
        bS1 = BT + (size_t)(n0 + rowB1) * Kld + kz * Khalf + chB1 * 8;
        bO0 = lin0 * 8; bO1 = lin1 * 8;
    }

#define STAGE_TILE(buf) do { \
        GLOAD_LDS16(aS,  &Al[(buf) * 2048 + aO]); \
        GLOAD_LDS16(bS0, &Bl[(buf) * 4096 + bO0]); \
        GLOAD_LDS16(bS1, &Bl[(buf) * 4096 + bO1]); \
        aS += 32; bS0 += 32; bS1 += 32; \
    } while (0)

    // ---- fragment read offsets (element units), swizzled to match staging
    int aoff[2], boff[4];
#pragma unroll
    for (int mi = 0; mi < 2; ++mi) {
        int row = wr * 32 + mi * 16 + r15;
        aoff[mi] = row * 32 + ((g4 ^ ((row >> 1) & 3)) * 8);
    }
#pragma unroll
    for (int ni = 0; ni < 4; ++ni) {
        int col = wc * 64 + ni * 16 + r15;
        boff[ni] = col * 32 + ((g4 ^ ((col >> 1) & 3)) * 8);
    }

    f32x4 acc[2][4];
#pragma unroll
    for (int mi = 0; mi < 2; ++mi)
#pragma unroll
        for (int ni = 0; ni < 4; ++ni) acc[mi][ni] = (f32x4){0.f, 0.f, 0.f, 0.f};

#define COMPUTE_TILE(buf) do { \
        const ushort* Ab = &Al[(buf) * 2048]; \
        const ushort* Bb = &Bl[(buf) * 4096]; \
        bf16x8 a0 = *(const bf16x8*)&Ab[aoff[0]]; \
        bf16x8 a1 = *(const bf16x8*)&Ab[aoff[1]]; \
        bf16x8 b0 = *(const bf16x8*)&Bb[boff[0]]; \
        bf16x8 b1 = *(const bf16x8*)&Bb[boff[1]]; \
        bf16x8 b2 = *(const bf16x8*)&Bb[boff[2]]; \
        bf16x8 b3 = *(const bf16x8*)&Bb[boff[3]]; \
        acc[0][0] = __builtin_amdgcn_mfma_f32_16x16x32_bf16(a0, b0, acc[0][0], 0, 0, 0); \
        acc[0][1] = __builtin_amdgcn_mfma_f32_16x16x32_bf16(a0, b1, acc[0][1], 0, 0, 0); \
        acc[0][2] = __builtin_amdgcn_mfma_f32_16x16x32_bf16(a0, b2, acc[0][2], 0, 0, 0); \
        acc[0][3] = __builtin_amdgcn_mfma_f32_16x16x32_bf16(a0, b3, acc[0][3], 0, 0, 0); \
        acc[1][0] = __builtin_amdgcn_mfma_f32_16x16x32_bf16(a1, b0, acc[1][0], 0, 0, 0); \
        acc[1][1] = __builtin_amdgcn_mfma_f32_16x16x32_bf16(a1, b1, acc[1][1], 0, 0, 0); \
        acc[1][2] = __builtin_amdgcn_mfma_f32_16x16x32_bf16(a1, b2, acc[1][2], 0, 0, 0); \
        acc[1][3] = __builtin_amdgcn_mfma_f32_16x16x32_bf16(a1, b3, acc[1][3], 0, 0, 0); \
    } while (0)

    const int NT = Khalf >> 5;
    STAGE_TILE(0);
    __syncthreads();                            // tile 0 ready
    for (int kt = 0; kt < NT; kt += 2) {
        if (kt + 1 < NT) STAGE_TILE(1);         // prefetch next before compute
        COMPUTE_TILE(0);
        __syncthreads();
        if (kt + 1 < NT) {
            if (kt + 2 < NT) STAGE_TILE(0);
            COMPUTE_TILE(1);
            __syncthreads();
        }
    }
#undef STAGE_TILE
#undef COMPUTE_TILE

    // ---- epilogue: bias (kz==0 only) + optional rope (linear -> per-half OK), partial store
    float vals[2][4][4];
#pragma unroll
    for (int ni = 0; ni < 4; ++ni) {
        int col = n0 + wc * 64 + ni * 16 + r15;
        float bv = (kz == 0 && col < Nreal) ? bias[col] : 0.f;
#pragma unroll
        for (int mi = 0; mi < 2; ++mi)
#pragma unroll
            for (int r = 0; r < 4; ++r) vals[mi][ni][r] = acc[mi][ni][r] + bv;
    }
    if (ROPE) {
        const int head = (n0 + wc * 64) >> 6;   // wave-half = exactly one 64-col head
        if (head < 72) {                         // q 0..63, k 64..71; v passthrough
#pragma unroll
            for (int mi = 0; mi < 2; ++mi)
#pragma unroll
                for (int r = 0; r < 4; ++r) {
                    int q = m0 + wr * 32 + mi * 16 + g4 * 4 + r;
#pragma unroll
                    for (int dp = 0; dp < 2; ++dp) {
                        int d = dp * 16 + r15;
                        float c = cosp[q * 32 + d];
                        float s = sinp[q * 32 + d];
                        float x1 = vals[mi][dp][r];
                        float x2 = vals[mi][dp + 2][r];
                        vals[mi][dp][r]     = x1 * c - x2 * s;
                        vals[mi][dp + 2][r] = x2 * c + x1 * s;
                    }
                }
        }
    }
    float* Cz = C + (size_t)kz * cstride;
#pragma unroll
    for (int ni = 0; ni < 4; ++ni) {
        int col = n0 + wc * 64 + ni * 16 + r15;
        if (col < Nreal) {
#pragma unroll
            for (int mi = 0; mi < 2; ++mi) {
                int row = m0 + wr * 32 + mi * 16 + g4 * 4;
#pragma unroll
                for (int r = 0; r < 4; ++r)
                    Cz[(size_t)(row + r) * ldC + col] = vals[mi][ni][r];
            }
        }
    }
}

// ---------------------------------------------------------------- MFMA flash attention
__global__ __launch_bounds__(512) void attn_mfma_kernel(
    const float* __restrict__ qkv, const float* __restrict__ sinks,
    ushort* __restrict__ attn_out)
{
    __shared__ __align__(16) ushort Kl[160][72];    // [key][d], pad 64->72 (2-way free)
    __shared__ __align__(16) ushort Vt[64][168];    // [d][key], pad 160->168 (2-way free)
    __shared__ __align__(16) ushort Pl[8][32][40];  // per-wave P chunk [row][32 keys], pad->40
    const int t = threadIdx.x;
    const int w = t >> 6;
    const int l = t & 63;
    const int g4 = l >> 4;
    const int r15 = l & 15;
    const int q0 = blockIdx.x * 32;
    const int hk = blockIdx.y;
    const int kbase = q0 - 128;

    // ---- stage K [160][64] f32->bf16 and V^T [64][160]
#pragma unroll
    for (int i = 0; i < 5; ++i) {
        int idx = i * 512 + t;             // 0..2559
        int row = idx >> 4;                // 0..159
        int c4 = (idx & 15) * 4;           // 0..60
        int j = kbase + row;
        float4 kv = make_float4(0.f, 0.f, 0.f, 0.f);
        float4 vv = make_float4(0.f, 0.f, 0.f, 0.f);
        if (j >= 0) {
            kv = *(const float4*)&qkv[(size_t)j * QKV_N + 4096 + hk * 64 + c4];
            vv = *(const float4*)&qkv[(size_t)j * QKV_N + 4608 + hk * 64 + c4];
        }
        ushort4 kp;
        kp.x = f2bf(kv.x); kp.y = f2bf(kv.y); kp.z = f2bf(kv.z); kp.w = f2bf(kv.w);
        *(ushort4*)&Kl[row][c4] = kp;
        Vt[c4 + 0][row] = f2bf(vv.x);
        Vt[c4 + 1][row] = f2bf(vv.y);
        Vt[c4 + 2][row] = f2bf(vv.z);
        Vt[c4 + 3][row] = f2bf(vv.w);
    }

    // ---- Q fragments (B operand: lane supplies col = score-row = r15+16ct, k = d)
    bf16x8 qf[2][2];
#pragma unroll
    for (int ct = 0; ct < 2; ++ct) {
        int R = w * 32 + ct * 16 + r15;
        int q = q0 + (R & 31);
        int hq = hk * 8 + (R >> 5);
        const float* qb = &qkv[(size_t)q * QKV_N + hq * 64];
#pragma unroll
        for (int s = 0; s < 2; ++s) {
            float4 a = *(const float4*)&qb[s * 32 + g4 * 8];
            float4 b = *(const float4*)&qb[s * 32 + g4 * 8 + 4];
            union { ushort u[8]; bf16x8 v; } pk;
            pk.u[0] = f2bf(a.x * SCALE_F); pk.u[1] = f2bf(a.y * SCALE_F);
            pk.u[2] = f2bf(a.z * SCALE_F); pk.u[3] = f2bf(a.w * SCALE_F);
            pk.u[4] = f2bf(b.x * SCALE_F); pk.u[5] = f2bf(b.y * SCALE_F);
            pk.u[6] = f2bf(b.z * SCALE_F); pk.u[7] = f2bf(b.w * SCALE_F);
            qf[ct][s] = pk.v;
        }
    }
    __syncthreads();

    // ---- S^T = K @ Q^T : D row = key = 16kt+4g4+r, col = score-row = 16ct+r15 (+32w)
    f32x4 sc[10][2];
#pragma unroll
    for (int kt = 0; kt < 10; ++kt) {
        sc[kt][0] = (f32x4){0.f, 0.f, 0.f, 0.f};
        sc[kt][1] = (f32x4){0.f, 0.f, 0.f, 0.f};
    }
#pragma unroll
    for (int kt = 0; kt < 10; ++kt) {
#pragma unroll
        for (int s = 0; s < 2; ++s) {
            bf16x8 kf = *(const bf16x8*)&Kl[kt * 16 + r15][s * 32 + g4 * 8];
            sc[kt][0] = __builtin_amdgcn_mfma_f32_16x16x32_bf16(kf, qf[0][s], sc[kt][0], 0, 0, 0);
            sc[kt][1] = __builtin_amdgcn_mfma_f32_16x16x32_bf16(kf, qf[1][s], sc[kt][1], 0, 0, 0);
        }
    }

    // ---- masked softmax, per score-row; fold sink and 1/denom (all lane-local)
    const int minkey = 128 - q0;          // key_local >= minkey  <=>  j >= 0
#pragma unroll
    for (int ct = 0; ct < 2; ++ct) {
        int R = w * 32 + ct * 16 + r15;
        int ql = R & 31;
        float snk = sinks[hk * 8 + (R >> 5)];
#pragma unroll
        for (int kt = 0; kt < 10; ++kt)
#pragma unroll
            for (int r = 0; r < 4; ++r) {
                int key = kt * 16 + g4 * 4 + r;
                // allowed: q_local < key <= q_local+128 (window+causal), key >= minkey (j>=0)
                bool ok = (key > ql) && (key <= ql + 128) && (key >= minkey);
                if (!ok) sc[kt][ct][r] = -1e30f;
            }
        float m = snk;
#pragma unroll
        for (int kt = 0; kt < 10; ++kt)
#pragma unroll
            for (int r = 0; r < 4; ++r) m = fmaxf(m, sc[kt][ct][r]);
        m = fmaxf(m, __shfl_xor(m, 16));
        m = fmaxf(m, __shfl_xor(m, 32));
        float sum = 0.f;
#pragma unroll
        for (int kt = 0; kt < 10; ++kt)
#pragma unroll
            for (int r = 0; r < 4; ++r) {
                float p = __expf(sc[kt][ct][r] - m);
                sc[kt][ct][r] = p;
                sum += p;
            }
        sum += __shfl_xor(sum, 16);
        sum += __shfl_xor(sum, 32);
        sum += __expf(snk - m);
        float iv = 1.0f / sum;
#pragma unroll
        for (int kt = 0; kt < 10; ++kt)
#pragma unroll
            for (int r = 0; r < 4; ++r) sc[kt][ct][r] *= iv;
    }

    // ---- PV: out[row][d] = sum_key P[row][key] * V[key][d]
    f32x4 pv[2][4];
#pragma unroll
    for (int mi = 0; mi < 2; ++mi)
#pragma unroll
        for (int ni = 0; ni < 4; ++ni) pv[mi][ni] = (f32x4){0.f, 0.f, 0.f, 0.f};

#pragma unroll
    for (int s = 0; s < 5; ++s) {
#pragma unroll
        for (int ct = 0; ct < 2; ++ct)
#pragma unroll
            for (int kh = 0; kh < 2; ++kh) {
                int kt = 2 * s + kh;
                ushort4 p4;
                p4.x = f2bf(sc[kt][ct][0]);
                p4.y = f2bf(sc[kt][ct][1]);
                p4.z = f2bf(sc[kt][ct][2]);
                p4.w = f2bf(sc[kt][ct][3]);
                *(ushort4*)&Pl[w][ct * 16 + r15][kh * 16 + g4 * 4] = p4;
            }
#pragma unroll
        for (int mi = 0; mi < 2; ++mi) {
            bf16x8 pf = *(const bf16x8*)&Pl[w][mi * 16 + r15][g4 * 8];
#pragma unroll
            for (int ni = 0; ni < 4; ++ni) {
                bf16x8 vf = *(const bf16x8*)&Vt[ni * 16 + r15][s * 32 + g4 * 8];
                pv[mi][ni] = __builtin_amdgcn_mfma_f32_16x16x32_bf16(pf, vf, pv[mi][ni], 0, 0, 0);
            }
        }
    }

    // ---- write attn output (bf16): D row = 16mi+4g4+r (+32w), col = d = 16ni+r15
#pragma unroll
    for (int mi = 0; mi < 2; ++mi)
#pragma unroll
        for (int r = 0; r < 4; ++r) {
            int R = w * 32 + mi * 16 + g4 * 4 + r;
            int q = q0 + (R & 31);
            int hq = hk * 8 + (R >> 5);
            ushort* ob = &attn_out[(size_t)q * ATTN_N + hq * 64 + r15];
#pragma unroll
            for (int ni = 0; ni < 4; ++ni)
                ob[ni * 16] = f2bf(pv[mi][ni][r]);
        }
}

// ---------------------------------------------------------------- launch
extern "C" void kernel_launch(void* const* d_in, const int* in_sizes, int n_in,
                              void* d_out, int out_size, void* d_ws, size_t ws_size,
                              hipStream_t stream)
{
    const float* hidden = (const float*)d_in[0];
    const float* cosp   = (const float*)d_in[1];
    const float* sinp   = (const float*)d_in[2];
    const float* w_qkv  = (const float*)d_in[3];
    const float* b_qkv  = (const float*)d_in[4];
    const float* w_o    = (const float*)d_in[5];
    const float* b_o    = (const float*)d_in[6];
    const float* sinks  = (const float*)d_in[7];
    // d_in[8]=k_cache, d_in[9]=v_cache (zero), d_in[10]=kv_len (==0): unused.

    char* ws = (char*)d_ws;
    size_t off = 0;
    ushort* wqkvT = (ushort*)(ws + off); off += (size_t)QKV_N * HID * 2;      // 29.5 MB
    ushort* woT   = (ushort*)(ws + off); off += (size_t)WO_NPAD * ATTN_N * 2; // 24.1 MB
    float*  qkv   = (float*)(ws + off);  off += (size_t)SEQ * QKV_N * 4;      // 20.0 MB
    ushort* hidden_b = (ushort*)(ws + off);                                    // union
    ushort* attn_b   = (ushort*)(ws + off); off += (size_t)SEQ * ATTN_N * 2;  //  8.0 MB
    float*  part  = (float*)(ws + off);  off += (size_t)2 * SEQ * QKV_N * 4;  // 41.9 MB (reused by gemm2)
    if (off > ws_size) return;  // fail visibly rather than corrupt

    // weight transposes + hidden convert
    transpose_convert<<<dim3(HID / 64, QKV_N / 64), 256, 0, stream>>>(w_qkv, wqkvT, HID, QKV_N);
    transpose_convert<<<dim3(ATTN_N / 64, WO_NPAD / 64), 256, 0, stream>>>(w_o, woT, ATTN_N, HID);
    convert_f32_bf16<<<2048, 256, 0, stream>>>(hidden, hidden_b, SEQ * HID / 4);

    // QKV projection, split-K x2 (rope per half — linear), then reduce
    gemm_sk<true><<<dim3(QKV_N / 128, SEQ / 64, 2), 256, 0, stream>>>(
        hidden_b, wqkvT, b_qkv, part, HID / 2, HID, QKV_N, QKV_N,
        (size_t)SEQ * QKV_N, cosp, sinp);
    reduce_add<<<2048, 256, 0, stream>>>(
        (const float4*)part, (const float4*)(part + (size_t)SEQ * QKV_N),
        (float4*)qkv, SEQ * QKV_N / 4);

    // MFMA flash attention: grid (q-tiles, kv-heads)
    attn_mfma_kernel<<<dim3(SEQ / 32, NKVH), 512, 0, stream>>>(qkv, sinks, attn_b);

    // output projection, split-K x2, then reduce into d_out
    gemm_sk<false><<<dim3(WO_NPAD / 128, SEQ / 64, 2), 256, 0, stream>>>(
        attn_b, woT, b_o, part, ATTN_N / 2, ATTN_N, HID, HID,
        (size_t)SEQ * HID, nullptr, nullptr);
    reduce_add<<<2048, 256, 0, stream>>>(
        (const float4*)part, (const float4*)(part + (size_t)SEQ * HID),
        (float4*)d_out, SEQ * HID / 4);
}

// Round 9
// 162.788 us; speedup vs baseline: 1.0683x; 1.0683x over previous
//
#include <hip/hip_runtime.h>
#include <hip/hip_bf16.h>

#define NQH 64
#define NKVH 8
#define DH 64
#define SEQ 1024
#define HID 2880
#define QKV_N 5120   // (NQ+2*NKV)*DH
#define ATTN_N 4096  // NQ*DH
#define WIN 128
#define WO_NPAD 2944 // 23*128
#define SCALE_F 0.125f

typedef __attribute__((ext_vector_type(8))) __bf16 bf16x8;
typedef __attribute__((ext_vector_type(4))) float f32x4;

#define GLOAD_LDS16(g, l) \
    __builtin_amdgcn_global_load_lds((const __attribute__((address_space(1))) void*)(g), \
                                     (__attribute__((address_space(3))) void*)(l), 16, 0, 0)

__device__ __forceinline__ ushort f2bf(float x) {
    union { float f; unsigned int u; } c; c.f = x;
    unsigned int u = c.u;
    unsigned int r = (u + 0x7FFFu + ((u >> 16) & 1u)) >> 16;
    return (ushort)r;
}

// ---------------------------------------------------------------- convert (plain)
__global__ __launch_bounds__(256) void convert_f32_bf16(
    const float* __restrict__ in, ushort* __restrict__ out, int n4)
{
    int idx = blockIdx.x * blockDim.x + threadIdx.x;
    int stride = gridDim.x * blockDim.x;
    for (int i = idx; i < n4; i += stride) {
        float4 v = reinterpret_cast<const float4*>(in)[i];
        ushort4 o;
        o.x = f2bf(v.x); o.y = f2bf(v.y); o.z = f2bf(v.z); o.w = f2bf(v.w);
        reinterpret_cast<ushort4*>(out)[i] = o;
    }
}

// ---------------------------------------------------------------- transpose+convert
// in: [K][N] f32  ->  out: [Npad][K] bf16 (rows >= N zero-filled). K,Npad multiples of 64.
__global__ __launch_bounds__(256) void transpose_convert(
    const float* __restrict__ in, ushort* __restrict__ out, int K, int N)
{
    __shared__ ushort tile[64][80];   // row stride 160B (16B-aligned for uint4)
    const int bk = blockIdx.x * 64;   // k tile origin
    const int bn = blockIdx.y * 64;   // n tile origin
    const int tid = threadIdx.x;
    const bool inb = bn < N;          // whole tile valid or whole tile pad (N % 64 == 0)

#pragma unroll
    for (int it = 0; it < 4; ++it) {
        int r = it * 16 + (tid >> 4);         // k offset 0..63
        int c4 = (tid & 15) * 4;              // n offset
        float4 v = make_float4(0.f, 0.f, 0.f, 0.f);
        if (inb) v = *(const float4*)&in[(size_t)(bk + r) * N + bn + c4];
        tile[c4 + 0][r] = f2bf(v.x);
        tile[c4 + 1][r] = f2bf(v.y);
        tile[c4 + 2][r] = f2bf(v.z);
        tile[c4 + 3][r] = f2bf(v.w);
    }
    __syncthreads();
#pragma unroll
    for (int it = 0; it < 2; ++it) {
        int nr = it * 32 + (tid >> 3);        // n offset 0..63
        int c8 = (tid & 7) * 8;               // k offset
        uint4 v = *(const uint4*)&tile[nr][c8];
        *(uint4*)&out[(size_t)(bn + nr) * K + bk + c8] = v;
    }
}

// ---------------------------------------------------------------- GEMM 128x128, BK=64, dbuf
// A: [M][K] bf16, BT: [Npad][K] bf16, C: [M][ldC] f32 (+bias), K % 64 == 0.
// 256 threads = 4 waves (2x2), wave tile 64x64 (4x4 frags, 32 MFMA / 16 ds_read per step):
// halves LDS-port + L2 bytes per FLOP vs 32x64 wave tile (R8 finding: pipe-bound, not TLP).
// R5 sync structure (prefetch-before-compute dbuf, __syncthreads). LDS 64 KB -> 2 blocks/CU.
// LDS row = 64 el = 128 B; slot swizzle = chunk ^ (row&7) (verified 0-conflict family).
template<bool ROPE>
__global__ __launch_bounds__(256) void gemm128sq(
    const ushort* __restrict__ A, const ushort* __restrict__ BT,
    const float* __restrict__ bias, float* __restrict__ C,
    int K, int ldC, int Nreal,
    const float* __restrict__ cosp, const float* __restrict__ sinp)
{
    __shared__ ushort Al[2 * 8192];   // 2 x 16 KB (128 x 64)
    __shared__ ushort Bl[2 * 8192];   // 2 x 16 KB
    const int t = threadIdx.x;
    const int lane = t & 63;
    const int w = t >> 6;
    const int wr = w >> 1, wc = w & 1;
    const int g4 = lane >> 4;
    const int r15 = lane & 15;

    // bijective XCD swizzle (nwg % 8 == 0; 8 m-tiles)
    const int flat = blockIdx.x + gridDim.x * blockIdx.y;
    const int per = (gridDim.x * gridDim.y) >> 3;
    const int virt = (flat & 7) * per + (flat >> 3);
    const int m0 = (virt & 7) * 128;
    const int n0 = (virt >> 3) * 128;

    // ---- staging: 4 A-chunks + 4 B-chunks per thread (16B each), inverse-swizzled source
    const ushort* aSrc[4]; const ushort* bSrc[4]; int dOff[4];
#pragma unroll
    for (int i = 0; i < 4; ++i) {
        int lin = i * 256 + t;
        int row = lin >> 3;                    // 0..127
        int ch = (lin & 7) ^ (row & 7);
        aSrc[i] = A  + (size_t)(m0 + row) * K + ch * 8;
        bSrc[i] = BT + (size_t)(n0 + row) * K + ch * 8;
        dOff[i] = lin * 8;
    }

#define STAGE_TILE(buf) do { \
        _Pragma("unroll") \
        for (int i = 0; i < 4; ++i) { \
            GLOAD_LDS16(aSrc[i], &Al[(buf) * 8192 + dOff[i]]); \
            GLOAD_LDS16(bSrc[i], &Bl[(buf) * 8192 + dOff[i]]); \
            aSrc[i] += 64; bSrc[i] += 64; \
        } \
    } while (0)

    // ---- fragment read offsets (element units), swizzled
    int aoff[4][2], boff[4][2];
#pragma unroll
    for (int i = 0; i < 4; ++i)
#pragma unroll
        for (int ks = 0; ks < 2; ++ks) {
            int row = wr * 64 + i * 16 + r15;
            aoff[i][ks] = row * 64 + (((ks * 4 + g4) ^ (row & 7)) * 8);
            int col = wc * 64 + i * 16 + r15;
            boff[i][ks] = col * 64 + (((ks * 4 + g4) ^ (col & 7)) * 8);
        }

    f32x4 acc[4][4];
#pragma unroll
    for (int mi = 0; mi < 4; ++mi)
#pragma unroll
        for (int ni = 0; ni < 4; ++ni) acc[mi][ni] = (f32x4){0.f, 0.f, 0.f, 0.f};

#define COMPUTE_TILE(buf) do { \
        const ushort* Ab = &Al[(buf) * 8192]; \
        const ushort* Bb = &Bl[(buf) * 8192]; \
        _Pragma("unroll") \
        for (int ks = 0; ks < 2; ++ks) { \
            bf16x8 af0 = *(const bf16x8*)&Ab[aoff[0][ks]]; \
            bf16x8 af1 = *(const bf16x8*)&Ab[aoff[1][ks]]; \
            bf16x8 af2 = *(const bf16x8*)&Ab[aoff[2][ks]]; \
            bf16x8 af3 = *(const bf16x8*)&Ab[aoff[3][ks]]; \
            bf16x8 bf0 = *(const bf16x8*)&Bb[boff[0][ks]]; \
            bf16x8 bf1 = *(const bf16x8*)&Bb[boff[1][ks]]; \
            bf16x8 bf2 = *(const bf16x8*)&Bb[boff[2][ks]]; \
            bf16x8 bf3 = *(const bf16x8*)&Bb[boff[3][ks]]; \
            acc[0][0] = __builtin_amdgcn_mfma_f32_16x16x32_bf16(af0, bf0, acc[0][0], 0, 0, 0); \
            acc[0][1] = __builtin_amdgcn_mfma_f32_16x16x32_bf16(af0, bf1, acc[0][1], 0, 0, 0); \
            acc[0][2] = __builtin_amdgcn_mfma_f32_16x16x32_bf16(af0, bf2, acc[0][2], 0, 0, 0); \
            acc[0][3] = __builtin_amdgcn_mfma_f32_16x16x32_bf16(af0, bf3, acc[0][3], 0, 0, 0); \
            acc[1][0] = __builtin_amdgcn_mfma_f32_16x16x32_bf16(af1, bf0, acc[1][0], 0, 0, 0); \
            acc[1][1] = __builtin_amdgcn_mfma_f32_16x16x32_bf16(af1, bf1, acc[1][1], 0, 0, 0); \
            acc[1][2] = __builtin_amdgcn_mfma_f32_16x16x32_bf16(af1, bf2, acc[1][2], 0, 0, 0); \
            acc[1][3] = __builtin_amdgcn_mfma_f32_16x16x32_bf16(af1, bf3, acc[1][3], 0, 0, 0); \
            acc[2][0] = __builtin_amdgcn_mfma_f32_16x16x32_bf16(af2, bf0, acc[2][0], 0, 0, 0); \
            acc[2][1] = __builtin_amdgcn_mfma_f32_16x16x32_bf16(af2, bf1, acc[2][1], 0, 0, 0); \
            acc[2][2] = __builtin_amdgcn_mfma_f32_16x16x32_bf16(af2, bf2, acc[2][2], 0, 0, 0); \
            acc[2][3] = __builtin_amdgcn_mfma_f32_16x16x32_bf16(af2, bf3, acc[2][3], 0, 0, 0); \
            acc[3][0] = __builtin_amdgcn_mfma_f32_16x16x32_bf16(af3, bf0, acc[3][0], 0, 0, 0); \
            acc[3][1] = __builtin_amdgcn_mfma_f32_16x16x32_bf16(af3, bf1, acc[3][1], 0, 0, 0); \
            acc[3][2] = __builtin_amdgcn_mfma_f32_16x16x32_bf16(af3, bf2, acc[3][2], 0, 0, 0); \
            acc[3][3] = __builtin_amdgcn_mfma_f32_16x16x32_bf16(af3, bf3, acc[3][3], 0, 0, 0); \
        } \
    } while (0)

    const int NT = K >> 6;
    STAGE_TILE(0);
    __syncthreads();                            // tile 0 ready
    for (int kt = 0; kt < NT; kt += 2) {
        if (kt + 1 < NT) STAGE_TILE(1);         // prefetch next before compute
        COMPUTE_TILE(0);
        __syncthreads();
        if (kt + 1 < NT) {
            if (kt + 2 < NT) STAGE_TILE(0);
            COMPUTE_TILE(1);
            __syncthreads();
        }
    }
#undef STAGE_TILE
#undef COMPUTE_TILE

    // ---- epilogue: bias + optional fused RoPE applied in-place on acc, f32 store
    // D frag: row = (lane>>4)*4 + r (+16*mi +64*wr +m0), col = lane&15 (+16*ni +64*wc +n0)
#pragma unroll
    for (int ni = 0; ni < 4; ++ni) {
        int col = n0 + wc * 64 + ni * 16 + r15;
        float bv = (col < Nreal) ? bias[col] : 0.f;
#pragma unroll
        for (int mi = 0; mi < 4; ++mi)
#pragma unroll
            for (int r = 0; r < 4; ++r) acc[mi][ni][r] += bv;
    }
    if (ROPE) {
        const int head = (n0 + wc * 64) >> 6;   // wave-half = exactly one 64-col head
        if (head < 72) {                         // q heads 0..63, k heads 64..71; v passthrough
#pragma unroll
            for (int mi = 0; mi < 4; ++mi)
#pragma unroll
                for (int r = 0; r < 4; ++r) {
                    int q = m0 + wr * 64 + mi * 16 + g4 * 4 + r;
#pragma unroll
                    for (int dp = 0; dp < 2; ++dp) {
                        int d = dp * 16 + r15;
                        float c = cosp[q * 32 + d];
                        float s = sinp[q * 32 + d];
                        float x1 = acc[mi][dp][r];
                        float x2 = acc[mi][dp + 2][r];
                        acc[mi][dp][r]     = x1 * c - x2 * s;
                        acc[mi][dp + 2][r] = x2 * c + x1 * s;
                    }
                }
        }
    }
#pragma unroll
    for (int ni = 0; ni < 4; ++ni) {
        int col = n0 + wc * 64 + ni * 16 + r15;
        if (col < Nreal) {
#pragma unroll
            for (int mi = 0; mi < 4; ++mi) {
                int row = m0 + wr * 64 + mi * 16 + g4 * 4;
#pragma unroll
                for (int r = 0; r < 4; ++r)
                    C[(size_t)(row + r) * ldC + col] = acc[mi][ni][r];
            }
        }
    }
}

// ---------------------------------------------------------------- MFMA flash attention
__global__ __launch_bounds__(512) void attn_mfma_kernel(
    const float* __restrict__ qkv, const float* __restrict__ sinks,
    ushort* __restrict__ attn_out)
{
    __shared__ __align__(16) ushort Kl[160][72];    // [key][d], pad 64->72 (2-way free)
    __shared__ __align__(16) ushort Vt[64][168];    // [d][key], pad 160->168 (2-way free)
    __shared__ __align__(16) ushort Pl[8][32][40];  // per-wave P chunk [row][32 keys], pad->40
    const int t = threadIdx.x;
    const int w = t >> 6;
    const int l = t & 63;
    const int g4 = l >> 4;
    const int r15 = l & 15;
    const int q0 = blockIdx.x * 32;
    const int hk = blockIdx.y;
    const int kbase = q0 - 128;

    // ---- stage K [160][64] f32->bf16 and V^T [64][160]
#pragma unroll
    for (int i = 0; i < 5; ++i) {
        int idx = i * 512 + t;             // 0..2559
        int row = idx >> 4;                // 0..159
        int c4 = (idx & 15) * 4;           // 0..60
        int j = kbase + row;
        float4 kv = make_float4(0.f, 0.f, 0.f, 0.f);
        float4 vv = make_float4(0.f, 0.f, 0.f, 0.f);
        if (j >= 0) {
            kv = *(const float4*)&qkv[(size_t)j * QKV_N + 4096 + hk * 64 + c4];
            vv = *(const float4*)&qkv[(size_t)j * QKV_N + 4608 + hk * 64 + c4];
        }
        ushort4 kp;
        kp.x = f2bf(kv.x); kp.y = f2bf(kv.y); kp.z = f2bf(kv.z); kp.w = f2bf(kv.w);
        *(ushort4*)&Kl[row][c4] = kp;
        Vt[c4 + 0][row] = f2bf(vv.x);
        Vt[c4 + 1][row] = f2bf(vv.y);
        Vt[c4 + 2][row] = f2bf(vv.z);
        Vt[c4 + 3][row] = f2bf(vv.w);
    }

    // ---- Q fragments (B operand: lane supplies col = score-row = r15+16ct, k = d)
    bf16x8 qf[2][2];
#pragma unroll
    for (int ct = 0; ct < 2; ++ct) {
        int R = w * 32 + ct * 16 + r15;
        int q = q0 + (R & 31);
        int hq = hk * 8 + (R >> 5);
        const float* qb = &qkv[(size_t)q * QKV_N + hq * 64];
#pragma unroll
        for (int s = 0; s < 2; ++s) {
            float4 a = *(const float4*)&qb[s * 32 + g4 * 8];
            float4 b = *(const float4*)&qb[s * 32 + g4 * 8 + 4];
            union { ushort u[8]; bf16x8 v; } pk;
            pk.u[0] = f2bf(a.x * SCALE_F); pk.u[1] = f2bf(a.y * SCALE_F);
            pk.u[2] = f2bf(a.z * SCALE_F); pk.u[3] = f2bf(a.w * SCALE_F);
            pk.u[4] = f2bf(b.x * SCALE_F); pk.u[5] = f2bf(b.y * SCALE_F);
            pk.u[6] = f2bf(b.z * SCALE_F); pk.u[7] = f2bf(b.w * SCALE_F);
            qf[ct][s] = pk.v;
        }
    }
    __syncthreads();

    // ---- S^T = K @ Q^T : D row = key = 16kt+4g4+r, col = score-row = 16ct+r15 (+32w)
    f32x4 sc[10][2];
#pragma unroll
    for (int kt = 0; kt < 10; ++kt) {
        sc[kt][0] = (f32x4){0.f, 0.f, 0.f, 0.f};
        sc[kt][1] = (f32x4){0.f, 0.f, 0.f, 0.f};
    }
#pragma unroll
    for (int kt = 0; kt < 10; ++kt) {
#pragma unroll
        for (int s = 0; s < 2; ++s) {
            bf16x8 kf = *(const bf16x8*)&Kl[kt * 16 + r15][s * 32 + g4 * 8];
            sc[kt][0] = __builtin_amdgcn_mfma_f32_16x16x32_bf16(kf, qf[0][s], sc[kt][0], 0, 0, 0);
            sc[kt][1] = __builtin_amdgcn_mfma_f32_16x16x32_bf16(kf, qf[1][s], sc[kt][1], 0, 0, 0);
        }
    }

    // ---- masked softmax, per score-row; fold sink and 1/denom (all lane-local)
    const int minkey = 128 - q0;          // key_local >= minkey  <=>  j >= 0
#pragma unroll
    for (int ct = 0; ct < 2; ++ct) {
        int R = w * 32 + ct * 16 + r15;
        int ql = R & 31;
        float snk = sinks[hk * 8 + (R >> 5)];
#pragma unroll
        for (int kt = 0; kt < 10; ++kt)
#pragma unroll
            for (int r = 0; r < 4; ++r) {
                int key = kt * 16 + g4 * 4 + r;
                // allowed: q_local < key <= q_local+128 (window+causal), key >= minkey (j>=0)
                bool ok = (key > ql) && (key <= ql + 128) && (key >= minkey);
                if (!ok) sc[kt][ct][r] = -1e30f;
            }
        float m = snk;
#pragma unroll
        for (int kt = 0; kt < 10; ++kt)
#pragma unroll
            for (int r = 0; r < 4; ++r) m = fmaxf(m, sc[kt][ct][r]);
        m = fmaxf(m, __shfl_xor(m, 16));
        m = fmaxf(m, __shfl_xor(m, 32));
        float sum = 0.f;
#pragma unroll
        for (int kt = 0; kt < 10; ++kt)
#pragma unroll
            for (int r = 0; r < 4; ++r) {
                float p = __expf(sc[kt][ct][r] - m);
                sc[kt][ct][r] = p;
                sum += p;
            }
        sum += __shfl_xor(sum, 16);
        sum += __shfl_xor(sum, 32);
        sum += __expf(snk - m);
        float iv = 1.0f / sum;
#pragma unroll
        for (int kt = 0; kt < 10; ++kt)
#pragma unroll
            for (int r = 0; r < 4; ++r) sc[kt][ct][r] *= iv;
    }

    // ---- PV: out[row][d] = sum_key P[row][key] * V[key][d]
    f32x4 pv[2][4];
#pragma unroll
    for (int mi = 0; mi < 2; ++mi)
#pragma unroll
        for (int ni = 0; ni < 4; ++ni) pv[mi][ni] = (f32x4){0.f, 0.f, 0.f, 0.f};

#pragma unroll
    for (int s = 0; s < 5; ++s) {
#pragma unroll
        for (int ct = 0; ct < 2; ++ct)
#pragma unroll
            for (int kh = 0; kh < 2; ++kh) {
                int kt = 2 * s + kh;
                ushort4 p4;
                p4.x = f2bf(sc[kt][ct][0]);
                p4.y = f2bf(sc[kt][ct][1]);
                p4.z = f2bf(sc[kt][ct][2]);
                p4.w = f2bf(sc[kt][ct][3]);
                *(ushort4*)&Pl[w][ct * 16 + r15][kh * 16 + g4 * 4] = p4;
            }
#pragma unroll
        for (int mi = 0; mi < 2; ++mi) {
            bf16x8 pf = *(const bf16x8*)&Pl[w][mi * 16 + r15][g4 * 8];
#pragma unroll
            for (int ni = 0; ni < 4; ++ni) {
                bf16x8 vf = *(const bf16x8*)&Vt[ni * 16 + r15][s * 32 + g4 * 8];
                pv[mi][ni] = __builtin_amdgcn_mfma_f32_16x16x32_bf16(pf, vf, pv[mi][ni], 0, 0, 0);
            }
        }
    }

    // ---- write attn output (bf16): D row = 16mi+4g4+r (+32w), col = d = 16ni+r15
#pragma unroll
    for (int mi = 0; mi < 2; ++mi)
#pragma unroll
        for (int r = 0; r < 4; ++r) {
            int R = w * 32 + mi * 16 + g4 * 4 + r;
            int q = q0 + (R & 31);
            int hq = hk * 8 + (R >> 5);
            ushort* ob = &attn_out[(size_t)q * ATTN_N + hq * 64 + r15];
#pragma unroll
            for (int ni = 0; ni < 4; ++ni)
                ob[ni * 16] = f2bf(pv[mi][ni][r]);
        }
}

// ---------------------------------------------------------------- launch
extern "C" void kernel_launch(void* const* d_in, const int* in_sizes, int n_in,
                              void* d_out, int out_size, void* d_ws, size_t ws_size,
                              hipStream_t stream)
{
    const float* hidden = (const float*)d_in[0];
    const float* cosp   = (const float*)d_in[1];
    const float* sinp   = (const float*)d_in[2];
    const float* w_qkv  = (const float*)d_in[3];
    const float* b_qkv  = (const float*)d_in[4];
    const float* w_o    = (const float*)d_in[5];
    const float* b_o    = (const float*)d_in[6];
    const float* sinks  = (const float*)d_in[7];
    // d_in[8]=k_cache, d_in[9]=v_cache (zero), d_in[10]=kv_len (==0): unused.

    char* ws = (char*)d_ws;
    size_t off = 0;
    ushort* wqkvT = (ushort*)(ws + off); off += (size_t)QKV_N * HID * 2;      // [5120][2880]
    ushort* woT   = (ushort*)(ws + off); off += (size_t)WO_NPAD * ATTN_N * 2; // [2944][4096]
    float*  qkv   = (float*)(ws + off);  off += (size_t)SEQ * QKV_N * 4;
    // union region: hidden_b (gemm1 A) then attn_b (gemm2 A) — lifetimes disjoint
    ushort* hidden_b = (ushort*)(ws + off);
    ushort* attn_b   = (ushort*)(ws + off); off += (size_t)SEQ * ATTN_N * 2;
    if (off > ws_size) return;  // fail visibly rather than corrupt

    // weight transposes + hidden convert
    transpose_convert<<<dim3(HID / 64, QKV_N / 64), 256, 0, stream>>>(w_qkv, wqkvT, HID, QKV_N);
    transpose_convert<<<dim3(ATTN_N / 64, WO_NPAD / 64), 256, 0, stream>>>(w_o, woT, ATTN_N, HID);
    convert_f32_bf16<<<2048, 256, 0, stream>>>(hidden, hidden_b, SEQ * HID / 4);

    // QKV projection with fused RoPE epilogue (grid 40x8 = 320, %8==0)
    gemm128sq<true><<<dim3(QKV_N / 128, SEQ / 128), 256, 0, stream>>>(
        hidden_b, wqkvT, b_qkv, qkv, HID, QKV_N, QKV_N, cosp, sinp);

    // MFMA flash attention: grid (q-tiles, kv-heads)
    attn_mfma_kernel<<<dim3(SEQ / 32, NKVH), 512, 0, stream>>>(qkv, sinks, attn_b);

    // output projection (grid 23x8 = 184, %8==0)
    gemm128sq<false><<<dim3(WO_NPAD / 128, SEQ / 128), 256, 0, stream>>>(
        attn_b, woT, b_o, (float*)d_out, ATTN_N, HID, HID, nullptr, nullptr);
}